// Round 12
// baseline (143.717 us; speedup 1.0000x reference)
//
#include <hip/hip_runtime.h>
#include <math.h>

#define SEQ   3072
#define DM    1024
#define NH    16
#define DH    64
#define WIN   128
#define DIL   4
#define TSUB  768      // SEQ / DIL

typedef __attribute__((ext_vector_type(8))) short    short8;   // 8 bf16
typedef __attribute__((ext_vector_type(8))) _Float16 half8;    // 8 fp16
typedef __attribute__((ext_vector_type(4))) _Float16 half4;    // 4 fp16 (64b)
typedef __attribute__((ext_vector_type(4))) float    floatx4;  // MFMA C/D

__device__ __forceinline__ float bf2f(unsigned short u) {
    return __uint_as_float(((unsigned)u) << 16);
}
__device__ __forceinline__ unsigned short f2bf(float f) {   // RNE, finite inputs
    unsigned u = __float_as_uint(f);
    return (unsigned short)((u + 0x7FFFu + ((u >> 16) & 1u)) >> 16);
}
__device__ __forceinline__ unsigned short f2h(float f) {
    _Float16 h = (_Float16)f;
    return __builtin_bit_cast(unsigned short, h);
}

// async global->LDS, 16B/lane. LDS dest is WAVE-UNIFORM base + lane*16
// (hardware adds the lane offset); global src is per-lane.
__device__ __forceinline__ void gload_lds16(const void* g, void* l) {
    __builtin_amdgcn_global_load_lds(
        (const __attribute__((address_space(1))) void*)g,
        (__attribute__((address_space(3))) void*)l, 16, 0, 0);
}

// ---------------------------------------------------------------------------
// fp32 -> bf16 conversion, R18 flat grid-stride (2048 blocks, no dead
// dispatches). Unchanged.
// ---------------------------------------------------------------------------
__global__ __launch_bounds__(256) void convert_kernel(
    const float* __restrict__ x,  const float* __restrict__ Wq,
    const float* __restrict__ Wk, const float* __restrict__ Wv,
    const float* __restrict__ Wo,
    ushort* __restrict__ xb,  ushort* __restrict__ Wqb,
    ushort* __restrict__ Wkb, ushort* __restrict__ Wvb,
    ushort* __restrict__ Wob)
{
    const int NX = SEQ * DM / 4;        // 786432 float4s in x
    const int NW = DM * DM / 4;         // 262144 float4s per weight
    const int NT = NX + 4 * NW;         // 1835008 total
    for (int i = blockIdx.x * 256 + threadIdx.x; i < NT; i += gridDim.x * 256) {
        const float* s; ushort* d; int o;
        if (i < NX)               { s = x;  d = xb;  o = i; }
        else if (i < NX + NW)     { s = Wq; d = Wqb; o = i - NX; }
        else if (i < NX + 2 * NW) { s = Wk; d = Wkb; o = i - NX - 2 * NW + NW; }
        else if (i < NX + 3 * NW) { s = Wv; d = Wvb; o = i - NX - 2 * NW; }
        else                      { s = Wo; d = Wob; o = i - NX - 3 * NW; }
        float4 v = ((const float4*)s)[o];
        ushort4 u = { f2bf(v.x), f2bf(v.y), f2bf(v.z), f2bf(v.w) };
        ((ushort4*)d)[o] = u;
    }
}

// ---------------------------------------------------------------------------
// QKV GEMM (R13/R14 best-measured config): 128x64 tile, 4 waves,
// counted-vmcnt two-barrier K-loop, XCD-aware block decode, 1152 blocks
// x 256 thr (3/CU resident at 48 KB LDS). Unchanged this round.
// ---------------------------------------------------------------------------
struct QkvSmem {
    ushort As[2][128][64];   // 2 x 16 KB
    ushort Bs[2][64][64];    // 2 x  8 KB
};

template<bool QSCALE, bool F16OUT>
__device__ __forceinline__ void gemm_qkv_body(QkvSmem& sm,
                                              const ushort* __restrict__ A,
                                              const ushort* __restrict__ W,
                                              const float* __restrict__ bias,
                                              const float* __restrict__ beta,
                                              ushort* __restrict__ C,
                                              int bx, int by)
{
    const int tid  = threadIdx.x;
    const int lane = tid & 63, w = tid >> 6;
    const int ln15 = lane & 15, quad = lane >> 4;
    const int wm = w >> 1, wn = w & 1;

    // DMA staging geometry: one gload_lds = 64 lanes x 16B = 8 rows of 128 B.
    // Wave w stages As rows w*32..w*32+31 (4 ops) + Bs rows w*16..+15 (2 ops).
    const int rl = lane >> 3, cl = lane & 7;
    const ushort* aRow[4];
#pragma unroll
    for (int i = 0; i < 4; ++i) {
        int row   = w * 32 + 8 * i + rl;
        int chunk = cl ^ ((row >> 1) & 7);              // inverse-swizzled src
        aRow[i] = A + (size_t)(by * 128 + row) * DM + chunk * 8;
    }
    const ushort* bRow[2];
#pragma unroll
    for (int i = 0; i < 2; ++i) {
        int row   = w * 16 + 8 * i + rl;
        int chunk = cl ^ ((row >> 1) & 7);
        bRow[i] = W + (size_t)(bx * 64 + row) * DM + chunk * 8;
    }

    // ---- preload epilogue scalars; force resident (vmcnt hygiene) ----------
    const int col0 = bx * 64 + wn * 32 + ln15;          // j=0 col
    float eb0 = bias[col0];
    float eb1 = bias[col0 + 16];                        // j=1 col
    float escale = QSCALE ? 0.125f * __expf(-beta[bx]) : 1.0f;  // head = col>>6 = bx
    asm volatile("" : "+v"(eb0), "+v"(eb1), "+v"(escale));

    const floatx4 zero = {0.f, 0.f, 0.f, 0.f};
    floatx4 acc[4][2];
#pragma unroll
    for (int i = 0; i < 4; ++i)
#pragma unroll
        for (int j = 0; j < 2; ++j) acc[i][j] = zero;

    // prologue: stage tile 0 into buffer 0 (no barrier; loop iter 0 waits)
#pragma unroll
    for (int i = 0; i < 4; ++i) gload_lds16(aRow[i], &sm.As[0][w * 32 + 8 * i][0]);
#pragma unroll
    for (int i = 0; i < 2; ++i) gload_lds16(bRow[i], &sm.Bs[0][w * 16 + 8 * i][0]);

    const int rf = (ln15 >> 1) & 7;                     // frag-read swizzle key
#pragma unroll 2
    for (int t = 0; t < 16; ++t) {
        const int cur = t & 1, nxt = cur ^ 1;
        if (t < 15) {                                   // issue prefetch FIRST
            const int ko = (t + 1) * 64;
#pragma unroll
            for (int i = 0; i < 4; ++i) gload_lds16(aRow[i] + ko, &sm.As[nxt][w * 32 + 8 * i][0]);
#pragma unroll
            for (int i = 0; i < 2; ++i) gload_lds16(bRow[i] + ko, &sm.Bs[nxt][w * 16 + 8 * i][0]);
            __builtin_amdgcn_sched_barrier(0);
            asm volatile("s_waitcnt vmcnt(6)" ::: "memory");  // oldest 6 = tile t
        } else {
            __builtin_amdgcn_sched_barrier(0);
            asm volatile("s_waitcnt vmcnt(0)" ::: "memory");  // last tile
        }
        __builtin_amdgcn_sched_barrier(0);
        __builtin_amdgcn_s_barrier();                   // all waves: tile t resident
#pragma unroll
        for (int s = 0; s < 2; ++s) {                   // two K=32 substeps
            short8 af[4], bf[2];
#pragma unroll
            for (int i = 0; i < 4; ++i)
                af[i] = *(const short8*)&sm.As[cur][wm * 64 + i * 16 + ln15][((s * 4 + quad) ^ rf) * 8];
#pragma unroll
            for (int j = 0; j < 2; ++j)
                bf[j] = *(const short8*)&sm.Bs[cur][wn * 32 + j * 16 + ln15][((s * 4 + quad) ^ rf) * 8];
#pragma unroll
            for (int i = 0; i < 4; ++i)
#pragma unroll
                for (int j = 0; j < 2; ++j)
                    acc[i][j] = __builtin_amdgcn_mfma_f32_16x16x32_bf16(af[i], bf[j], acc[i][j], 0, 0, 0);
        }
        asm volatile("s_waitcnt lgkmcnt(0)" ::: "memory");
        __builtin_amdgcn_sched_barrier(0);
        __builtin_amdgcn_s_barrier();                   // all waves: reads done
    }

#pragma unroll
    for (int j = 0; j < 2; ++j) {
        const int col = col0 + j * 16;
        const float b = j ? eb1 : eb0;
#pragma unroll
        for (int i = 0; i < 4; ++i) {
            const int row0 = by * 128 + wm * 64 + i * 16 + quad * 4;
#pragma unroll
            for (int rg = 0; rg < 4; ++rg) {
                float vv = (acc[i][j][rg] + b) * escale;
                C[(size_t)(row0 + rg) * DM + col] = F16OUT ? f2h(vv) : f2bf(vv);
            }
        }
    }
}

// 1-D grid 1152. XCD-aware decode: xcd = lid&7 (HW round-robin, m09);
// each XCD owns A-panel groups G = xcd*9 + s/16 (G = z*24+by), bx = s%16.
__global__ __launch_bounds__(256, 3) void qkv_kernel(
    const ushort* __restrict__ xb,
    const ushort* __restrict__ Wqb, const float* __restrict__ bq,
    const ushort* __restrict__ Wkb, const float* __restrict__ bk,
    const ushort* __restrict__ Wvb, const float* __restrict__ bv,
    const float* __restrict__ beta,
    ushort* __restrict__ q, ushort* __restrict__ k, ushort* __restrict__ v)
{
    __shared__ QkvSmem sm;                     // single allocation, shared by
    const int lid = blockIdx.x;                // ALL instantiations below
    const int xcd = lid & 7, s = lid >> 3;     // s: 0..143
    const int G   = xcd * 9 + (s >> 4);        // A-panel group 0..71
    const int by  = G % 24, z = G / 24;
    const int bx  = s & 15;
    const ushort* W = (z == 0) ? Wqb : (z == 1) ? Wkb : Wvb;
    const float*  b = (z == 0) ? bq  : (z == 1) ? bk  : bv;
    ushort*       C = (z == 0) ? q   : (z == 1) ? k   : v;
    if (z == 0)
        gemm_qkv_body<true , false>(sm, xb, W, b, beta, C, bx, by);
    else if (z == 1)
        gemm_qkv_body<false, false>(sm, xb, W, b, nullptr, C, bx, by);
    else
        gemm_qkv_body<false, true >(sm, xb, W, b, nullptr, C, bx, by);
}

// ---------------------------------------------------------------------------
// Output GEMM, R20: 64x64 tile, TWO waves (128 thr), wave tile 64x32
// (acc 4x2 -- the proven qkv wave shape). R11 post-mortem: attn nulls show
// kernels are population-saturated; out's inefficiency is MFMA-per-barrier-
// interval (8/wave/iter vs qkv's 16 for the same-shape GEMM). This doubles
// it WITHOUT reducing block population (768 blocks, 3/CU demand unchanged;
// LDS 32 KB -> residency cap rises 3->5). Per wave/iter: 16 MFMA, 8 staging
// ops, vmcnt(8). Same total staged bytes, same XCD swizzle, same swizzle
// keys (all row offsets mult. of 16 -> key = (ln15>>1)&7 invariant).
// ---------------------------------------------------------------------------
__global__ __launch_bounds__(128, 2) void out_kernel(
    const ushort* __restrict__ ctxb, const ushort* __restrict__ Wob,
    const float* __restrict__ bo, float* __restrict__ out)
{
    __shared__ ushort As[2][64][64];    // 16 KB
    __shared__ ushort Bs[2][64][64];    // 16 KB

    const int tid  = threadIdx.x;
    const int lane = tid & 63, w = tid >> 6;    // w in {0,1}
    const int ln15 = lane & 15, quad = lane >> 4;
    const int wn = w;                           // N-split: wave w owns cols w*32..+31

    const int lid = blockIdx.x;
    const int xcd = lid & 7, s0 = lid >> 3;    // s0: 0..95
    const int by  = xcd * 6 + (s0 >> 4);       // A-panel group 0..47
    const int bx  = s0 & 15;

    // staging: wave w stages A rows w*32..+31 (4 ops) and B rows w*32..+31 (4 ops)
    const int rl = lane >> 3, cl = lane & 7;
    const ushort* aRow[4]; const ushort* bRow[4];
#pragma unroll
    for (int i = 0; i < 4; ++i) {
        int row   = w * 32 + 8 * i + rl;
        int chunk = cl ^ ((row >> 1) & 7);
        aRow[i] = ctxb + (size_t)(by * 64 + row) * DM + chunk * 8;
        bRow[i] = Wob  + (size_t)(bx * 64 + row) * DM + chunk * 8;
    }

    // preload epilogue scalars; force resident (vmcnt hygiene: the asm makes
    // the compiler drain these loads BEFORE the staging ops are issued)
    const int col0 = bx * 64 + wn * 32 + ln15;
    float eb0 = bo[col0];
    float eb1 = bo[col0 + 16];
    asm volatile("" : "+v"(eb0), "+v"(eb1));

    const floatx4 zero = {0.f, 0.f, 0.f, 0.f};
    floatx4 acc[4][2];
#pragma unroll
    for (int i = 0; i < 4; ++i)
#pragma unroll
        for (int j = 0; j < 2; ++j) acc[i][j] = zero;

    // prologue (no barrier; loop iter 0 waits)
#pragma unroll
    for (int i = 0; i < 4; ++i) gload_lds16(aRow[i], &As[0][w * 32 + 8 * i][0]);
#pragma unroll
    for (int i = 0; i < 4; ++i) gload_lds16(bRow[i], &Bs[0][w * 32 + 8 * i][0]);

    const int rf = (ln15 >> 1) & 7;
#pragma unroll 2
    for (int t = 0; t < 16; ++t) {
        const int cur = t & 1, nxt = cur ^ 1;
        if (t < 15) {
            const int ko = (t + 1) * 64;
#pragma unroll
            for (int i = 0; i < 4; ++i) gload_lds16(aRow[i] + ko, &As[nxt][w * 32 + 8 * i][0]);
#pragma unroll
            for (int i = 0; i < 4; ++i) gload_lds16(bRow[i] + ko, &Bs[nxt][w * 32 + 8 * i][0]);
            __builtin_amdgcn_sched_barrier(0);
            asm volatile("s_waitcnt vmcnt(8)" ::: "memory");  // oldest 8 = tile t
        } else {
            __builtin_amdgcn_sched_barrier(0);
            asm volatile("s_waitcnt vmcnt(0)" ::: "memory");
        }
        __builtin_amdgcn_sched_barrier(0);
        __builtin_amdgcn_s_barrier();
#pragma unroll
        for (int s = 0; s < 2; ++s) {
            short8 af[4], bf[2];
#pragma unroll
            for (int i = 0; i < 4; ++i)
                af[i] = *(const short8*)&As[cur][i * 16 + ln15][((s * 4 + quad) ^ rf) * 8];
#pragma unroll
            for (int j = 0; j < 2; ++j)
                bf[j] = *(const short8*)&Bs[cur][wn * 32 + j * 16 + ln15][((s * 4 + quad) ^ rf) * 8];
#pragma unroll
            for (int i = 0; i < 4; ++i)
#pragma unroll
                for (int j = 0; j < 2; ++j)
                    acc[i][j] = __builtin_amdgcn_mfma_f32_16x16x32_bf16(af[i], bf[j], acc[i][j], 0, 0, 0);
        }
        asm volatile("s_waitcnt lgkmcnt(0)" ::: "memory");
        __builtin_amdgcn_sched_barrier(0);
        __builtin_amdgcn_s_barrier();
    }

#pragma unroll
    for (int j = 0; j < 2; ++j) {
        const int col = col0 + j * 16;
        const float b = j ? eb1 : eb0;
#pragma unroll
        for (int i = 0; i < 4; ++i) {
            const int row0 = by * 64 + i * 16 + quad * 4;
#pragma unroll
            for (int rg = 0; rg < 4; ++rg)
                out[(size_t)(row0 + rg) * DM + col] = acc[i][j][rg] + b;
        }
    }
}

// ---------------------------------------------------------------------------
// MFMA attention (R19 structure, unchanged): flash-style in-register softmax,
// V staged at kernel top (separate Vs buffer), counted-vmcnt barrier 1,
// no vmcnt drain at barrier 2, V latency hidden at barrier 3.
// ---------------------------------------------------------------------------
struct AttnSmem {
    ushort Ks[160 * 64];    // 20480 B  [key][dg]; dg holds dims 8*(dg^(key&7))
    ushort Vs[40 * 256];    // 20480 B  40 tr-read tiles (fp16)
    ushort P[32][168];      // 10752 B  exp(S - m_half) fp16, stride 336 B
    float  mh[2][32];       // per-half row max
    float  sh[2][32];       // per-half row sum
    float  f0[32], f1[32], rsum[32];
};

__global__ __launch_bounds__(256, 3) void attn_kernel(
    const ushort* __restrict__ q, const ushort* __restrict__ k,
    const ushort* __restrict__ v, ushort* __restrict__ ctx)
{
    __shared__ AttnSmem sm;

    const int tid  = threadIdx.x;
    const int lane = tid & 63, w = tid >> 6;
    const int ln15 = lane & 15, quad = lane >> 4;

    // XCD decode: 1536 blocks = 8 xcd x 2 heads x (24 t0 x 4 r)
    const int lid = blockIdx.x;
    const int xcd = lid & 7, s0 = lid >> 3;     // s0: 0..191
    const int h   = xcd * 2 + (s0 / 96);
    const int rem = s0 % 96;
    const int t0  = (rem % 24) * 32;
    const int r   = rem / 24;
    const int hoff = h * DH;

    // ---- stage K (160 keys x 64 dims) via glds, 5 ops/wave -----------------
    {
        const int kr = lane >> 3;                   // key-in-op 0..7
        const int swz = ((lane & 7) ^ kr) * 8;      // XOR swizzle on global dim
#pragma unroll
        for (int ci = w * 5; ci < w * 5 + 5; ++ci) {
            int key = ci * 8 + kr;
            long grow = 4L * (t0 - 128 + key) + r;  // may be negative -> q buffer
            gload_lds16(k + grow * DM + hoff + swz, &sm.Ks[ci * 512]);
        }
    }
    __builtin_amdgcn_sched_barrier(0);

    // ---- Q A-frags direct from global (wave w owns qtile w>>1) -------------
    const int qt = w >> 1;
    short8 qf0, qf1;
    {
        int qrow = qt * 16 + ln15;
        const ushort* gq = q + (4L * (t0 + qrow) + r) * DM + hoff + quad * 8;
        qf0 = *(const short8*)gq;
        qf1 = *(const short8*)(gq + 32);
    }
    __builtin_amdgcn_sched_barrier(0);

    // ---- stage V (fp16) into tr-read layout via glds, 5 ops/wave -----------
    // Issued HERE (separate Vs buffer): in flight across QK^T + combine.
    {
#pragma unroll
        for (int i = 0; i < 5; ++i) {
            const int o  = w * 5 + i;               // op 0..19
            const int c  = o * 64 + lane;           // 16-B chunk index, 0..1279
            const int hh = c & 1, jj = (c >> 1) & 3, qq = (c >> 3) & 3;
            const int T  = c >> 5;                  // tile 0..39
            const int p  = T & 1, dtt = (T >> 1) & 3, kc = T >> 3;
            const int key = kc * 32 + qq * 8 + p * 4 + jj;
            const int dim = dtt * 16 + hh * 8;
            long grow = 4L * (t0 - 128 + key) + r;  // may be negative -> masked
            gload_lds16(v + grow * DM + hoff + dim, &sm.Vs[o * 512]);
        }
    }
    __builtin_amdgcn_sched_barrier(0);

    // barrier 1: wait K(5)+Q(2) retire; V's 5 ops stay in flight.
    asm volatile("s_waitcnt vmcnt(5)" ::: "memory");
    __builtin_amdgcn_sched_barrier(0);
    __builtin_amdgcn_s_barrier();

    // ---- QK^T + in-register per-half softmax -------------------------------
    {
        const floatx4 zero = {0.f, 0.f, 0.f, 0.f};
        const int kt0 = (w & 1) * 5;
        const int lb  = ln15 & 7;
        float sv[5][4];
#pragma unroll
        for (int kk2 = 0; kk2 < 5; ++kk2) {
            const int kt  = kt0 + kk2;
            const int key = kt * 16 + ln15;
            short8 b0 = *(const short8*)&sm.Ks[key * 64 + ((quad ^ lb) << 3)];
            short8 b1 = *(const short8*)&sm.Ks[key * 64 + (((4 + quad) ^ lb) << 3)];
            floatx4 acc = zero;
            acc = __builtin_amdgcn_mfma_f32_16x16x32_bf16(qf0, b0, acc, 0, 0, 0);
            acc = __builtin_amdgcn_mfma_f32_16x16x32_bf16(qf1, b1, acc, 0, 0, 0);
            const int tp = t0 - 128 + key;          // key slot time
#pragma unroll
            for (int rg = 0; rg < 4; ++rg) {
                int tq = t0 + qt * 16 + quad * 4 + rg;
                bool ok = (tp >= 0) && (tp <= tq) && (tp > tq - WIN);
                sv[kk2][rg] = ok ? acc[rg] : -1e30f;
            }
        }
        // per-row (max, sum) over this wave's half; write P = exp(s - m_h)
        float mh4[4], sh4[4];
#pragma unroll
        for (int rg = 0; rg < 4; ++rg) {
            float m = sv[0][rg];
#pragma unroll
            for (int kk2 = 1; kk2 < 5; ++kk2) m = fmaxf(m, sv[kk2][rg]);
#pragma unroll
            for (int o = 1; o < 16; o <<= 1) m = fmaxf(m, __shfl_xor(m, o));
            float s = 0.f;
            const int qrow = qt * 16 + quad * 4 + rg;
#pragma unroll
            for (int kk2 = 0; kk2 < 5; ++kk2) {
                float e = __expf(sv[kk2][rg] - m);
                s += e;
                sm.P[qrow][(kt0 + kk2) * 16 + ln15] = f2h(e);
            }
#pragma unroll
            for (int o = 1; o < 16; o <<= 1) s += __shfl_xor(s, o);
            mh4[rg] = m; sh4[rg] = s;
        }
        if (ln15 == 0) {
#pragma unroll
            for (int rg = 0; rg < 4; ++rg) {
                const int qrow = qt * 16 + quad * 4 + rg;
                sm.mh[w & 1][qrow] = mh4[rg];
                sm.sh[w & 1][qrow] = sh4[rg];
            }
        }
    }

    // barrier 2: P + partials visible; V still in flight (NO vmcnt drain).
    asm volatile("s_waitcnt lgkmcnt(0)" ::: "memory");
    __builtin_amdgcn_sched_barrier(0);
    __builtin_amdgcn_s_barrier();

    // ---- combine: per-row global max, half factors, 1/sum ------------------
    if (tid < 32) {
        float m0 = sm.mh[0][tid], m1 = sm.mh[1][tid];
        float s0 = sm.sh[0][tid], s1 = sm.sh[1][tid];
        float m  = fmaxf(m0, m1);
        float g0 = __expf(m0 - m), g1 = __expf(m1 - m);
        sm.f0[tid] = g0;
        sm.f1[tid] = g1;
        sm.rsum[tid] = 1.0f / (s0 * g0 + s1 * g1);
    }

    // barrier 3: V resident (latency hidden) + factors visible.
    asm volatile("s_waitcnt vmcnt(0) lgkmcnt(0)" ::: "memory");
    __builtin_amdgcn_sched_barrier(0);
    __builtin_amdgcn_s_barrier();

    // ---- PV: wave w -> qtile w&1, dtiles (w>>1)*2 .. +1 --------------------
    {
        const floatx4 zero = {0.f, 0.f, 0.f, 0.f};
        const int qtp = w & 1, dh = w >> 1;
        const int prow = qtp * 16 + ln15;
        const float vf0 = sm.f0[prow], vf1 = sm.f1[prow];
        floatx4 o0 = zero, o1 = zero;
        // byte addr: tile(kc,dt,p) at kc*4096 + dt*1024 + p*512; dt0 = dh*2.
        const unsigned vbase =
            (unsigned)(size_t)(__attribute__((address_space(3))) ushort*)&sm.Vs[0]
            + lane * 8 + dh * 2048;
#pragma unroll
        for (int kc = 0; kc < 5; ++kc) {
            half8 pa = *(const half8*)&sm.P[prow][kc * 32 + quad * 8];
            // keys kc*32+quad*8 .. +7 are half-pure (boundary 80 is 8-aligned)
            float ff = (kc < 2) ? vf0 : (kc > 2) ? vf1 : (quad < 2 ? vf0 : vf1);
            _Float16 fh = (_Float16)ff;
            pa *= fh;                                   // rescale to exp(s - m)
            half4 a0, a1, b0, b1;
            asm volatile(
                "ds_read_b64_tr_b16 %0, %4\n\t"
                "ds_read_b64_tr_b16 %1, %4 offset:512\n\t"
                "ds_read_b64_tr_b16 %2, %4 offset:1024\n\t"
                "ds_read_b64_tr_b16 %3, %4 offset:1536\n\t"
                "s_waitcnt lgkmcnt(0)"
                : "=&v"(a0), "=&v"(a1), "=&v"(b0), "=&v"(b1)
                : "v"(vbase + kc * 4096));
            __builtin_amdgcn_sched_barrier(0);      // rule #18 fence
            half8 vb0 = __builtin_shufflevector(a0, a1, 0, 1, 2, 3, 4, 5, 6, 7);
            half8 vb1 = __builtin_shufflevector(b0, b1, 0, 1, 2, 3, 4, 5, 6, 7);
            o0 = __builtin_amdgcn_mfma_f32_16x16x32_f16(pa, vb0, o0, 0, 0, 0);
            o1 = __builtin_amdgcn_mfma_f32_16x16x32_f16(pa, vb1, o1, 0, 0, 0);
        }
#pragma unroll
        for (int rg = 0; rg < 4; ++rg) {
            int qrow = qtp * 16 + quad * 4 + rg;
            float rs = sm.rsum[qrow];
            long orow = 4L * (t0 + qrow) + r;
            ushort* cp = ctx + orow * DM + hoff + dh * 32 + ln15;
            cp[0]  = f2bf(o0[rg] * rs);
            cp[16] = f2bf(o1[rg] * rs);
        }
    }
}

// ---------------------------------------------------------------------------
// ws layout: q, k, ctx bf16; v fp16; x, Wq, Wk, Wv, Wo bf16.
// ---------------------------------------------------------------------------
extern "C" void kernel_launch(void* const* d_in, const int* in_sizes, int n_in,
                              void* d_out, int out_size, void* d_ws, size_t ws_size,
                              hipStream_t stream)
{
    const float* x    = (const float*)d_in[0];
    const float* beta = (const float*)d_in[1];
    const float* Wq   = (const float*)d_in[2];
    const float* bq   = (const float*)d_in[3];
    const float* Wk   = (const float*)d_in[4];
    const float* bk   = (const float*)d_in[5];
    const float* Wv   = (const float*)d_in[6];
    const float* bv   = (const float*)d_in[7];
    const float* Wo   = (const float*)d_in[8];
    const float* bo   = (const float*)d_in[9];

    ushort* qb   = (ushort*)d_ws;
    ushort* kb   = qb   + (size_t)SEQ * DM;
    ushort* vb   = kb   + (size_t)SEQ * DM;
    ushort* ctxb = vb   + (size_t)SEQ * DM;
    ushort* xb   = ctxb + (size_t)SEQ * DM;
    ushort* Wqb  = xb   + (size_t)SEQ * DM;
    ushort* Wkb  = Wqb  + (size_t)DM * DM;
    ushort* Wvb  = Wkb  + (size_t)DM * DM;
    ushort* Wob  = Wvb  + (size_t)DM * DM;
    float*  out  = (float*)d_out;

    convert_kernel<<<dim3(2048), 256, 0, stream>>>(x, Wq, Wk, Wv, Wo, xb, Wqb, Wkb, Wvb, Wob);

    qkv_kernel<<<dim3(1152), 256, 0, stream>>>(xb, Wqb, bq, Wkb, bk, Wvb, bv, beta, qb, kb, vb);

    attn_kernel<<<dim3(1536), 256, 0, stream>>>(qb, kb, vb, ctxb);

    out_kernel<<<dim3(768), 128, 0, stream>>>(ctxb, Wob, bo, out);
}

// Round 13
// 139.685 us; speedup vs baseline: 1.0289x; 1.0289x over previous
//
#include <hip/hip_runtime.h>
#include <math.h>

#define SEQ   3072
#define DM    1024
#define NH    16
#define DH    64
#define WIN   128
#define DIL   4
#define TSUB  768      // SEQ / DIL

typedef __attribute__((ext_vector_type(8))) short    short8;   // 8 bf16
typedef __attribute__((ext_vector_type(8))) _Float16 half8;    // 8 fp16
typedef __attribute__((ext_vector_type(4))) _Float16 half4;    // 4 fp16 (64b)
typedef __attribute__((ext_vector_type(4))) float    floatx4;  // MFMA C/D

__device__ __forceinline__ float bf2f(unsigned short u) {
    return __uint_as_float(((unsigned)u) << 16);
}
__device__ __forceinline__ unsigned short f2bf(float f) {   // RNE, finite inputs
    unsigned u = __float_as_uint(f);
    return (unsigned short)((u + 0x7FFFu + ((u >> 16) & 1u)) >> 16);
}
__device__ __forceinline__ unsigned short f2h(float f) {
    _Float16 h = (_Float16)f;
    return __builtin_bit_cast(unsigned short, h);
}

// async global->LDS, 16B/lane. LDS dest is WAVE-UNIFORM base + lane*16
// (hardware adds the lane offset); global src is per-lane.
__device__ __forceinline__ void gload_lds16(const void* g, void* l) {
    __builtin_amdgcn_global_load_lds(
        (const __attribute__((address_space(1))) void*)g,
        (__attribute__((address_space(3))) void*)l, 16, 0, 0);
}

// ---------------------------------------------------------------------------
// fp32 -> bf16 conversion, flat grid-stride (2048 blocks, no dead
// dispatches). R10-verified (+3.3 us vs 2-D grid).
// ---------------------------------------------------------------------------
__global__ __launch_bounds__(256) void convert_kernel(
    const float* __restrict__ x,  const float* __restrict__ Wq,
    const float* __restrict__ Wk, const float* __restrict__ Wv,
    const float* __restrict__ Wo,
    ushort* __restrict__ xb,  ushort* __restrict__ Wqb,
    ushort* __restrict__ Wkb, ushort* __restrict__ Wvb,
    ushort* __restrict__ Wob)
{
    const int NX = SEQ * DM / 4;        // 786432 float4s in x
    const int NW = DM * DM / 4;         // 262144 float4s per weight
    const int NT = NX + 4 * NW;         // 1835008 total
    for (int i = blockIdx.x * 256 + threadIdx.x; i < NT; i += gridDim.x * 256) {
        const float* s; ushort* d; int o;
        if (i < NX)               { s = x;  d = xb;  o = i; }
        else if (i < NX + NW)     { s = Wq; d = Wqb; o = i - NX; }
        else if (i < NX + 2 * NW) { s = Wk; d = Wkb; o = i - NX - 2 * NW + NW; }
        else if (i < NX + 3 * NW) { s = Wv; d = Wvb; o = i - NX - 2 * NW; }
        else                      { s = Wo; d = Wob; o = i - NX - 3 * NW; }
        float4 v = ((const float4*)s)[o];
        ushort4 u = { f2bf(v.x), f2bf(v.y), f2bf(v.z), f2bf(v.w) };
        ((ushort4*)d)[o] = u;
    }
}

// ---------------------------------------------------------------------------
// QKV GEMM (best-measured config): 128x64 tile, 4 waves, counted-vmcnt
// two-barrier K-loop, XCD-aware block decode, 1152 blocks x 256 thr
// (3/CU resident at 48 KB LDS).
// R12 lesson (3rd confirmation): never shrink the synchronized wave pool --
// 2-wave/bigger-tile variants all lost (R6 qkv, R7 attn, R12 out).
// ---------------------------------------------------------------------------
struct QkvSmem {
    ushort As[2][128][64];   // 2 x 16 KB
    ushort Bs[2][64][64];    // 2 x  8 KB
};

template<bool QSCALE, bool F16OUT>
__device__ __forceinline__ void gemm_qkv_body(QkvSmem& sm,
                                              const ushort* __restrict__ A,
                                              const ushort* __restrict__ W,
                                              const float* __restrict__ bias,
                                              const float* __restrict__ beta,
                                              ushort* __restrict__ C,
                                              int bx, int by)
{
    const int tid  = threadIdx.x;
    const int lane = tid & 63, w = tid >> 6;
    const int ln15 = lane & 15, quad = lane >> 4;
    const int wm = w >> 1, wn = w & 1;

    // DMA staging geometry: one gload_lds = 64 lanes x 16B = 8 rows of 128 B.
    // Wave w stages As rows w*32..w*32+31 (4 ops) + Bs rows w*16..+15 (2 ops).
    const int rl = lane >> 3, cl = lane & 7;
    const ushort* aRow[4];
#pragma unroll
    for (int i = 0; i < 4; ++i) {
        int row   = w * 32 + 8 * i + rl;
        int chunk = cl ^ ((row >> 1) & 7);              // inverse-swizzled src
        aRow[i] = A + (size_t)(by * 128 + row) * DM + chunk * 8;
    }
    const ushort* bRow[2];
#pragma unroll
    for (int i = 0; i < 2; ++i) {
        int row   = w * 16 + 8 * i + rl;
        int chunk = cl ^ ((row >> 1) & 7);
        bRow[i] = W + (size_t)(bx * 64 + row) * DM + chunk * 8;
    }

    // ---- preload epilogue scalars; force resident (vmcnt hygiene) ----------
    const int col0 = bx * 64 + wn * 32 + ln15;          // j=0 col
    float eb0 = bias[col0];
    float eb1 = bias[col0 + 16];                        // j=1 col
    float escale = QSCALE ? 0.125f * __expf(-beta[bx]) : 1.0f;  // head = col>>6 = bx
    asm volatile("" : "+v"(eb0), "+v"(eb1), "+v"(escale));

    const floatx4 zero = {0.f, 0.f, 0.f, 0.f};
    floatx4 acc[4][2];
#pragma unroll
    for (int i = 0; i < 4; ++i)
#pragma unroll
        for (int j = 0; j < 2; ++j) acc[i][j] = zero;

    // prologue: stage tile 0 into buffer 0 (no barrier; loop iter 0 waits)
#pragma unroll
    for (int i = 0; i < 4; ++i) gload_lds16(aRow[i], &sm.As[0][w * 32 + 8 * i][0]);
#pragma unroll
    for (int i = 0; i < 2; ++i) gload_lds16(bRow[i], &sm.Bs[0][w * 16 + 8 * i][0]);

    const int rf = (ln15 >> 1) & 7;                     // frag-read swizzle key
#pragma unroll 2
    for (int t = 0; t < 16; ++t) {
        const int cur = t & 1, nxt = cur ^ 1;
        if (t < 15) {                                   // issue prefetch FIRST
            const int ko = (t + 1) * 64;
#pragma unroll
            for (int i = 0; i < 4; ++i) gload_lds16(aRow[i] + ko, &sm.As[nxt][w * 32 + 8 * i][0]);
#pragma unroll
            for (int i = 0; i < 2; ++i) gload_lds16(bRow[i] + ko, &sm.Bs[nxt][w * 16 + 8 * i][0]);
            __builtin_amdgcn_sched_barrier(0);
            asm volatile("s_waitcnt vmcnt(6)" ::: "memory");  // oldest 6 = tile t
        } else {
            __builtin_amdgcn_sched_barrier(0);
            asm volatile("s_waitcnt vmcnt(0)" ::: "memory");  // last tile
        }
        __builtin_amdgcn_sched_barrier(0);
        __builtin_amdgcn_s_barrier();                   // all waves: tile t resident
#pragma unroll
        for (int s = 0; s < 2; ++s) {                   // two K=32 substeps
            short8 af[4], bf[2];
#pragma unroll
            for (int i = 0; i < 4; ++i)
                af[i] = *(const short8*)&sm.As[cur][wm * 64 + i * 16 + ln15][((s * 4 + quad) ^ rf) * 8];
#pragma unroll
            for (int j = 0; j < 2; ++j)
                bf[j] = *(const short8*)&sm.Bs[cur][wn * 32 + j * 16 + ln15][((s * 4 + quad) ^ rf) * 8];
#pragma unroll
            for (int i = 0; i < 4; ++i)
#pragma unroll
                for (int j = 0; j < 2; ++j)
                    acc[i][j] = __builtin_amdgcn_mfma_f32_16x16x32_bf16(af[i], bf[j], acc[i][j], 0, 0, 0);
        }
        asm volatile("s_waitcnt lgkmcnt(0)" ::: "memory");
        __builtin_amdgcn_sched_barrier(0);
        __builtin_amdgcn_s_barrier();                   // all waves: reads done
    }

#pragma unroll
    for (int j = 0; j < 2; ++j) {
        const int col = col0 + j * 16;
        const float b = j ? eb1 : eb0;
#pragma unroll
        for (int i = 0; i < 4; ++i) {
            const int row0 = by * 128 + wm * 64 + i * 16 + quad * 4;
#pragma unroll
            for (int rg = 0; rg < 4; ++rg) {
                float vv = (acc[i][j][rg] + b) * escale;
                C[(size_t)(row0 + rg) * DM + col] = F16OUT ? f2h(vv) : f2bf(vv);
            }
        }
    }
}

// 1-D grid 1152. XCD-aware decode: xcd = lid&7 (HW round-robin, m09);
// each XCD owns A-panel groups G = xcd*9 + s/16 (G = z*24+by), bx = s%16.
__global__ __launch_bounds__(256, 3) void qkv_kernel(
    const ushort* __restrict__ xb,
    const ushort* __restrict__ Wqb, const float* __restrict__ bq,
    const ushort* __restrict__ Wkb, const float* __restrict__ bk,
    const ushort* __restrict__ Wvb, const float* __restrict__ bv,
    const float* __restrict__ beta,
    ushort* __restrict__ q, ushort* __restrict__ k, ushort* __restrict__ v)
{
    __shared__ QkvSmem sm;                     // single allocation, shared by
    const int lid = blockIdx.x;                // ALL instantiations below
    const int xcd = lid & 7, s = lid >> 3;     // s: 0..143
    const int G   = xcd * 9 + (s >> 4);        // A-panel group 0..71
    const int by  = G % 24, z = G / 24;
    const int bx  = s & 15;
    const ushort* W = (z == 0) ? Wqb : (z == 1) ? Wkb : Wvb;
    const float*  b = (z == 0) ? bq  : (z == 1) ? bk  : bv;
    ushort*       C = (z == 0) ? q   : (z == 1) ? k   : v;
    if (z == 0)
        gemm_qkv_body<true , false>(sm, xb, W, b, beta, C, bx, by);
    else if (z == 1)
        gemm_qkv_body<false, false>(sm, xb, W, b, nullptr, C, bx, by);
    else
        gemm_qkv_body<false, true >(sm, xb, W, b, nullptr, C, bx, by);
}

// ---------------------------------------------------------------------------
// Output GEMM (REVERT to R10/R11 4-wave version -- R12's 2-wave variant
// regressed 3.9 us): 64x64 tile, BK=64, 4 waves 2x2, 1-D grid 768 (3/CU).
// Counted-vmcnt loop (LOADS_PER_TILE=4) + XCD swizzle.
// ---------------------------------------------------------------------------
__global__ __launch_bounds__(256, 3) void out_kernel(
    const ushort* __restrict__ ctxb, const ushort* __restrict__ Wob,
    const float* __restrict__ bo, float* __restrict__ out)
{
    __shared__ ushort As[2][64][64];    // 16 KB
    __shared__ ushort Bs[2][64][64];    // 16 KB

    const int tid  = threadIdx.x;
    const int lane = tid & 63, w = tid >> 6;
    const int ln15 = lane & 15, quad = lane >> 4;
    const int wm = w >> 1, wn = w & 1;

    const int lid = blockIdx.x;
    const int xcd = lid & 7, s0 = lid >> 3;    // s0: 0..95
    const int by  = xcd * 6 + (s0 >> 4);       // A-panel group 0..47
    const int bx  = s0 & 15;

    // wave w stages As rows w*16..+15 (2 ops) and Bs rows w*16..+15 (2 ops)
    const int rl = lane >> 3, cl = lane & 7;
    const ushort* aRow[2]; const ushort* bRow[2];
#pragma unroll
    for (int i = 0; i < 2; ++i) {
        int row   = w * 16 + 8 * i + rl;
        int chunk = cl ^ ((row >> 1) & 7);
        aRow[i] = ctxb + (size_t)(by * 64 + row) * DM + chunk * 8;
        bRow[i] = Wob  + (size_t)(bx * 64 + row) * DM + chunk * 8;
    }

    // preload epilogue scalars; force resident (vmcnt hygiene)
    const int col0 = bx * 64 + wn * 32 + ln15;
    float eb0 = bo[col0];
    float eb1 = bo[col0 + 16];
    asm volatile("" : "+v"(eb0), "+v"(eb1));

    const floatx4 zero = {0.f, 0.f, 0.f, 0.f};
    floatx4 acc[2][2];
#pragma unroll
    for (int i = 0; i < 2; ++i)
#pragma unroll
        for (int j = 0; j < 2; ++j) acc[i][j] = zero;

    // prologue (no barrier; loop iter 0 waits)
#pragma unroll
    for (int i = 0; i < 2; ++i) {
        gload_lds16(aRow[i], &As[0][w * 16 + 8 * i][0]);
        gload_lds16(bRow[i], &Bs[0][w * 16 + 8 * i][0]);
    }

    const int rf = (ln15 >> 1) & 7;
#pragma unroll 2
    for (int t = 0; t < 16; ++t) {
        const int cur = t & 1, nxt = cur ^ 1;
        if (t < 15) {
            const int ko = (t + 1) * 64;
#pragma unroll
            for (int i = 0; i < 2; ++i) {
                gload_lds16(aRow[i] + ko, &As[nxt][w * 16 + 8 * i][0]);
                gload_lds16(bRow[i] + ko, &Bs[nxt][w * 16 + 8 * i][0]);
            }
            __builtin_amdgcn_sched_barrier(0);
            asm volatile("s_waitcnt vmcnt(4)" ::: "memory");  // oldest 4 = tile t
        } else {
            __builtin_amdgcn_sched_barrier(0);
            asm volatile("s_waitcnt vmcnt(0)" ::: "memory");
        }
        __builtin_amdgcn_sched_barrier(0);
        __builtin_amdgcn_s_barrier();
#pragma unroll
        for (int s = 0; s < 2; ++s) {
            short8 af[2], bf[2];
#pragma unroll
            for (int i = 0; i < 2; ++i)
                af[i] = *(const short8*)&As[cur][wm * 32 + i * 16 + ln15][((s * 4 + quad) ^ rf) * 8];
#pragma unroll
            for (int j = 0; j < 2; ++j)
                bf[j] = *(const short8*)&Bs[cur][wn * 32 + j * 16 + ln15][((s * 4 + quad) ^ rf) * 8];
#pragma unroll
            for (int i = 0; i < 2; ++i)
#pragma unroll
                for (int j = 0; j < 2; ++j)
                    acc[i][j] = __builtin_amdgcn_mfma_f32_16x16x32_bf16(af[i], bf[j], acc[i][j], 0, 0, 0);
        }
        asm volatile("s_waitcnt lgkmcnt(0)" ::: "memory");
        __builtin_amdgcn_sched_barrier(0);
        __builtin_amdgcn_s_barrier();
    }

#pragma unroll
    for (int j = 0; j < 2; ++j) {
        const int col = col0 + j * 16;
        const float b = j ? eb1 : eb0;
#pragma unroll
        for (int i = 0; i < 2; ++i) {
            const int row0 = by * 64 + wm * 32 + i * 16 + quad * 4;
#pragma unroll
            for (int rg = 0; rg < 4; ++rg)
                out[(size_t)(row0 + rg) * DM + col] = acc[i][j][rg] + b;
        }
    }
}

// ---------------------------------------------------------------------------
// MFMA attention (R19 structure): flash-style in-register softmax, V staged
// at kernel top (separate Vs buffer), counted-vmcnt barrier 1, no vmcnt
// drain at barrier 2, V latency hidden at barrier 3.
// ---------------------------------------------------------------------------
struct AttnSmem {
    ushort Ks[160 * 64];    // 20480 B  [key][dg]; dg holds dims 8*(dg^(key&7))
    ushort Vs[40 * 256];    // 20480 B  40 tr-read tiles (fp16)
    ushort P[32][168];      // 10752 B  exp(S - m_half) fp16, stride 336 B
    float  mh[2][32];       // per-half row max
    float  sh[2][32];       // per-half row sum
    float  f0[32], f1[32], rsum[32];
};

__global__ __launch_bounds__(256, 3) void attn_kernel(
    const ushort* __restrict__ q, const ushort* __restrict__ k,
    const ushort* __restrict__ v, ushort* __restrict__ ctx)
{
    __shared__ AttnSmem sm;

    const int tid  = threadIdx.x;
    const int lane = tid & 63, w = tid >> 6;
    const int ln15 = lane & 15, quad = lane >> 4;

    // XCD decode: 1536 blocks = 8 xcd x 2 heads x (24 t0 x 4 r)
    const int lid = blockIdx.x;
    const int xcd = lid & 7, s0 = lid >> 3;     // s0: 0..191
    const int h   = xcd * 2 + (s0 / 96);
    const int rem = s0 % 96;
    const int t0  = (rem % 24) * 32;
    const int r   = rem / 24;
    const int hoff = h * DH;

    // ---- stage K (160 keys x 64 dims) via glds, 5 ops/wave -----------------
    {
        const int kr = lane >> 3;                   // key-in-op 0..7
        const int swz = ((lane & 7) ^ kr) * 8;      // XOR swizzle on global dim
#pragma unroll
        for (int ci = w * 5; ci < w * 5 + 5; ++ci) {
            int key = ci * 8 + kr;
            long grow = 4L * (t0 - 128 + key) + r;  // may be negative -> q buffer
            gload_lds16(k + grow * DM + hoff + swz, &sm.Ks[ci * 512]);
        }
    }
    __builtin_amdgcn_sched_barrier(0);

    // ---- Q A-frags direct from global (wave w owns qtile w>>1) -------------
    const int qt = w >> 1;
    short8 qf0, qf1;
    {
        int qrow = qt * 16 + ln15;
        const ushort* gq = q + (4L * (t0 + qrow) + r) * DM + hoff + quad * 8;
        qf0 = *(const short8*)gq;
        qf1 = *(const short8*)(gq + 32);
    }
    __builtin_amdgcn_sched_barrier(0);

    // ---- stage V (fp16) into tr-read layout via glds, 5 ops/wave -----------
    // Issued HERE (separate Vs buffer): in flight across QK^T + combine.
    {
#pragma unroll
        for (int i = 0; i < 5; ++i) {
            const int o  = w * 5 + i;               // op 0..19
            const int c  = o * 64 + lane;           // 16-B chunk index, 0..1279
            const int hh = c & 1, jj = (c >> 1) & 3, qq = (c >> 3) & 3;
            const int T  = c >> 5;                  // tile 0..39
            const int p  = T & 1, dtt = (T >> 1) & 3, kc = T >> 3;
            const int key = kc * 32 + qq * 8 + p * 4 + jj;
            const int dim = dtt * 16 + hh * 8;
            long grow = 4L * (t0 - 128 + key) + r;  // may be negative -> masked
            gload_lds16(v + grow * DM + hoff + dim, &sm.Vs[o * 512]);
        }
    }
    __builtin_amdgcn_sched_barrier(0);

    // barrier 1: wait K(5)+Q(2) retire; V's 5 ops stay in flight.
    asm volatile("s_waitcnt vmcnt(5)" ::: "memory");
    __builtin_amdgcn_sched_barrier(0);
    __builtin_amdgcn_s_barrier();

    // ---- QK^T + in-register per-half softmax -------------------------------
    {
        const floatx4 zero = {0.f, 0.f, 0.f, 0.f};
        const int kt0 = (w & 1) * 5;
        const int lb  = ln15 & 7;
        float sv[5][4];
#pragma unroll
        for (int kk2 = 0; kk2 < 5; ++kk2) {
            const int kt  = kt0 + kk2;
            const int key = kt * 16 + ln15;
            short8 b0 = *(const short8*)&sm.Ks[key * 64 + ((quad ^ lb) << 3)];
            short8 b1 = *(const short8*)&sm.Ks[key * 64 + (((4 + quad) ^ lb) << 3)];
            floatx4 acc = zero;
            acc = __builtin_amdgcn_mfma_f32_16x16x32_bf16(qf0, b0, acc, 0, 0, 0);
            acc = __builtin_amdgcn_mfma_f32_16x16x32_bf16(qf1, b1, acc, 0, 0, 0);
            const int tp = t0 - 128 + key;          // key slot time
#pragma unroll
            for (int rg = 0; rg < 4; ++rg) {
                int tq = t0 + qt * 16 + quad * 4 + rg;
                bool ok = (tp >= 0) && (tp <= tq) && (tp > tq - WIN);
                sv[kk2][rg] = ok ? acc[rg] : -1e30f;
            }
        }
        // per-row (max, sum) over this wave's half; write P = exp(s - m_h)
        float mh4[4], sh4[4];
#pragma unroll
        for (int rg = 0; rg < 4; ++rg) {
            float m = sv[0][rg];
#pragma unroll
            for (int kk2 = 1; kk2 < 5; ++kk2) m = fmaxf(m, sv[kk2][rg]);
#pragma unroll
            for (int o = 1; o < 16; o <<= 1) m = fmaxf(m, __shfl_xor(m, o));
            float s = 0.f;
            const int qrow = qt * 16 + quad * 4 + rg;
#pragma unroll
            for (int kk2 = 0; kk2 < 5; ++kk2) {
                float e = __expf(sv[kk2][rg] - m);
                s += e;
                sm.P[qrow][(kt0 + kk2) * 16 + ln15] = f2h(e);
            }
#pragma unroll
            for (int o = 1; o < 16; o <<= 1) s += __shfl_xor(s, o);
            mh4[rg] = m; sh4[rg] = s;
        }
        if (ln15 == 0) {
#pragma unroll
            for (int rg = 0; rg < 4; ++rg) {
                const int qrow = qt * 16 + quad * 4 + rg;
                sm.mh[w & 1][qrow] = mh4[rg];
                sm.sh[w & 1][qrow] = sh4[rg];
            }
        }
    }

    // barrier 2: P + partials visible; V still in flight (NO vmcnt drain).
    asm volatile("s_waitcnt lgkmcnt(0)" ::: "memory");
    __builtin_amdgcn_sched_barrier(0);
    __builtin_amdgcn_s_barrier();

    // ---- combine: per-row global max, half factors, 1/sum ------------------
    if (tid < 32) {
        float m0 = sm.mh[0][tid], m1 = sm.mh[1][tid];
        float s0 = sm.sh[0][tid], s1 = sm.sh[1][tid];
        float m  = fmaxf(m0, m1);
        float g0 = __expf(m0 - m), g1 = __expf(m1 - m);
        sm.f0[tid] = g0;
        sm.f1[tid] = g1;
        sm.rsum[tid] = 1.0f / (s0 * g0 + s1 * g1);
    }

    // barrier 3: V resident (latency hidden) + factors visible.
    asm volatile("s_waitcnt vmcnt(0) lgkmcnt(0)" ::: "memory");
    __builtin_amdgcn_sched_barrier(0);
    __builtin_amdgcn_s_barrier();

    // ---- PV: wave w -> qtile w&1, dtiles (w>>1)*2 .. +1 --------------------
    {
        const floatx4 zero = {0.f, 0.f, 0.f, 0.f};
        const int qtp = w & 1, dh = w >> 1;
        const int prow = qtp * 16 + ln15;
        const float vf0 = sm.f0[prow], vf1 = sm.f1[prow];
        floatx4 o0 = zero, o1 = zero;
        // byte addr: tile(kc,dt,p) at kc*4096 + dt*1024 + p*512; dt0 = dh*2.
        const unsigned vbase =
            (unsigned)(size_t)(__attribute__((address_space(3))) ushort*)&sm.Vs[0]
            + lane * 8 + dh * 2048;
#pragma unroll
        for (int kc = 0; kc < 5; ++kc) {
            half8 pa = *(const half8*)&sm.P[prow][kc * 32 + quad * 8];
            // keys kc*32+quad*8 .. +7 are half-pure (boundary 80 is 8-aligned)
            float ff = (kc < 2) ? vf0 : (kc > 2) ? vf1 : (quad < 2 ? vf0 : vf1);
            _Float16 fh = (_Float16)ff;
            pa *= fh;                                   // rescale to exp(s - m)
            half4 a0, a1, b0, b1;
            asm volatile(
                "ds_read_b64_tr_b16 %0, %4\n\t"
                "ds_read_b64_tr_b16 %1, %4 offset:512\n\t"
                "ds_read_b64_tr_b16 %2, %4 offset:1024\n\t"
                "ds_read_b64_tr_b16 %3, %4 offset:1536\n\t"
                "s_waitcnt lgkmcnt(0)"
                : "=&v"(a0), "=&v"(a1), "=&v"(b0), "=&v"(b1)
                : "v"(vbase + kc * 4096));
            __builtin_amdgcn_sched_barrier(0);      // rule #18 fence
            half8 vb0 = __builtin_shufflevector(a0, a1, 0, 1, 2, 3, 4, 5, 6, 7);
            half8 vb1 = __builtin_shufflevector(b0, b1, 0, 1, 2, 3, 4, 5, 6, 7);
            o0 = __builtin_amdgcn_mfma_f32_16x16x32_f16(pa, vb0, o0, 0, 0, 0);
            o1 = __builtin_amdgcn_mfma_f32_16x16x32_f16(pa, vb1, o1, 0, 0, 0);
        }
#pragma unroll
        for (int rg = 0; rg < 4; ++rg) {
            int qrow = qtp * 16 + quad * 4 + rg;
            float rs = sm.rsum[qrow];
            long orow = 4L * (t0 + qrow) + r;
            ushort* cp = ctx + orow * DM + hoff + dh * 32 + ln15;
            cp[0]  = f2bf(o0[rg] * rs);
            cp[16] = f2bf(o1[rg] * rs);
        }
    }
}

// ---------------------------------------------------------------------------
// ws layout: q, k, ctx bf16; v fp16; x, Wq, Wk, Wv, Wo bf16.
// ---------------------------------------------------------------------------
extern "C" void kernel_launch(void* const* d_in, const int* in_sizes, int n_in,
                              void* d_out, int out_size, void* d_ws, size_t ws_size,
                              hipStream_t stream)
{
    const float* x    = (const float*)d_in[0];
    const float* beta = (const float*)d_in[1];
    const float* Wq   = (const float*)d_in[2];
    const float* bq   = (const float*)d_in[3];
    const float* Wk   = (const float*)d_in[4];
    const float* bk   = (const float*)d_in[5];
    const float* Wv   = (const float*)d_in[6];
    const float* bv   = (const float*)d_in[7];
    const float* Wo   = (const float*)d_in[8];
    const float* bo   = (const float*)d_in[9];

    ushort* qb   = (ushort*)d_ws;
    ushort* kb   = qb   + (size_t)SEQ * DM;
    ushort* vb   = kb   + (size_t)SEQ * DM;
    ushort* ctxb = vb   + (size_t)SEQ * DM;
    ushort* xb   = ctxb + (size_t)SEQ * DM;
    ushort* Wqb  = xb   + (size_t)SEQ * DM;
    ushort* Wkb  = Wqb  + (size_t)DM * DM;
    ushort* Wvb  = Wkb  + (size_t)DM * DM;
    ushort* Wob  = Wvb  + (size_t)DM * DM;
    float*  out  = (float*)d_out;

    convert_kernel<<<dim3(2048), 256, 0, stream>>>(x, Wq, Wk, Wv, Wo, xb, Wqb, Wkb, Wvb, Wob);

    qkv_kernel<<<dim3(1152), 256, 0, stream>>>(xb, Wqb, bq, Wkb, bk, Wvb, bv, beta, qb, kb, vb);

    attn_kernel<<<dim3(1536), 256, 0, stream>>>(qb, kb, vb, ctxb);

    out_kernel<<<dim3(768), 256, 0, stream>>>(ctxb, Wob, bo, out);
}